// Round 3
// baseline (234.593 us; speedup 1.0000x reference)
//
#include <hip/hip_runtime.h>
#include <stdint.h>

#define L_SEQ 4096
#define NBATCH 2
#define HID 1024
#define HEADS 16
#define DH 64
#define Z_DIM 32
#define NBLK 64
#define NROWS 8192  // L_SEQ * NBATCH
#define NSPLIT 8    // head split-K factor (8 kblocks per split)

typedef float f32x4 __attribute__((ext_vector_type(4)));
typedef short short8 __attribute__((ext_vector_type(8)));

typedef const uint32_t __attribute__((address_space(1))) *gas_ptr;
typedef uint32_t __attribute__((address_space(3))) *las_ptr;

__device__ __forceinline__ ushort f2bf(float f) {
  uint32_t u = __float_as_uint(f);
  uint32_t r = (u + 0x7FFFu + ((u >> 16) & 1u)) >> 16;  // RNE
  return (ushort)r;
}

__device__ __forceinline__ void gload_lds16(const void* g, void* l) {
  __builtin_amdgcn_global_load_lds((gas_ptr)g, (las_ptr)l, 16, 0, 0);
}

// ---------------- f32 -> bf16 conversion ----------------
__global__ void cvt_f32_bf16(const float* __restrict__ src, ushort* __restrict__ dst, int n4) {
  int i = blockIdx.x * blockDim.x + threadIdx.x;
  const int stride = gridDim.x * blockDim.x;
  for (; i < n4; i += stride) {
    float4 v = ((const float4*)src)[i];
    ushort4 o;
    o.x = f2bf(v.x); o.y = f2bf(v.y); o.z = f2bf(v.z); o.w = f2bf(v.w);
    ((ushort4*)dst)[i] = o;
  }
}

// ---------------- bf16 NT GEMM: C = X @ W^T + bias ----------------
// 128x128 tile, BK=64, 4 waves (2x2), 16x16x32 MFMA, global_load_lds staging
// with XOR-swizzled LDS (pre-swizzled global source, swizzled ds_read).
// FINAL=0: grid.z selects Q/K/V; Q/K scatter to [z][l][d]; V goes through an
//          LDS transpose and is written coalesced to vt[z][d][l].
// FINAL=1: epilogue writes f32 row-major [8192][1024] (d_out).
template <int FINAL>
__global__ __launch_bounds__(256)
void gemm_bt(const ushort* __restrict__ X,
             const ushort* __restrict__ W0, const ushort* __restrict__ W1,
             const ushort* __restrict__ W2,
             const float* __restrict__ b0, const float* __restrict__ b1,
             const float* __restrict__ b2,
             ushort* __restrict__ Qo, ushort* __restrict__ Ko,
             ushort* __restrict__ Vo, float* __restrict__ Fo) {
  const int tid = threadIdx.x;
  const int w = tid >> 6, l = tid & 63;
  const int lr = l & 15, lg = l >> 4;
  const int wr = w >> 1, wc = w & 1;
  const int mbase = blockIdx.y * 128;
  const int nbase = blockIdx.x * 128;
  const int zid = FINAL ? 0 : blockIdx.z;

  const ushort* W = FINAL ? W0 : (zid == 0 ? W0 : (zid == 1 ? W1 : W2));
  const float*  B = FINAL ? b0 : (zid == 0 ? b0 : (zid == 1 ? b1 : b2));

  __shared__ ushort lAB[2 * 128 * 64];  // lA = lAB, lB = lAB + 8192
  ushort* lA = lAB;
  ushort* lB = lAB + 128 * 64;

  f32x4 acc[4][4];
#pragma unroll
  for (int m = 0; m < 4; ++m)
#pragma unroll
    for (int n = 0; n < 4; ++n) acc[m][n] = (f32x4){0.f, 0.f, 0.f, 0.f};

  for (int k0 = 0; k0 < HID; k0 += 64) {
#pragma unroll
    for (int s = 0; s < 4; ++s) {
      const int chunk = s * 256 + tid;        // 0..1023, 16B chunks
      const int row = chunk >> 3, cc = chunk & 7;
      const int scc = cc ^ (row & 7);         // pre-swizzled global source
      void* dstA = &lA[(s * 256 + (tid & ~63)) * 8];
      void* dstB = &lB[(s * 256 + (tid & ~63)) * 8];
      gload_lds16(X + (size_t)(mbase + row) * HID + k0 + scc * 8, dstA);
      gload_lds16(W + (size_t)(nbase + row) * HID + k0 + scc * 8, dstB);
    }
    __syncthreads();
#pragma unroll
    for (int kk = 0; kk < 2; ++kk) {
      const int kc = kk * 4 + lg;  // 16B-chunk index within the row (0..7)
      short8 af[4], bfr[4];
#pragma unroll
      for (int m = 0; m < 4; ++m) {
        const int row = wr * 64 + m * 16 + lr;
        af[m] = *(const short8*)&lA[row * 64 + ((kc ^ (row & 7)) << 3)];
      }
#pragma unroll
      for (int n = 0; n < 4; ++n) {
        const int row = wc * 64 + n * 16 + lr;
        bfr[n] = *(const short8*)&lB[row * 64 + ((kc ^ (row & 7)) << 3)];
      }
#pragma unroll
      for (int m = 0; m < 4; ++m)
#pragma unroll
        for (int n = 0; n < 4; ++n)
          acc[m][n] = __builtin_amdgcn_mfma_f32_16x16x32_bf16(af[m], bfr[n], acc[m][n], 0, 0, 0);
    }
    __syncthreads();
  }

  if (!FINAL && zid == 2) {
    // ---- V epilogue: LDS transpose, coalesced 16B writes to Vt[z][d][l] ----
    float biasn[4];
#pragma unroll
    for (int n = 0; n < 4; ++n) biasn[n] = B[nbase + wc * 64 + n * 16 + lr];
    __syncthreads();  // everyone done reading lA/lB
#pragma unroll
    for (int nb = 0; nb < 2; ++nb) {
      // stage: LDS[colLocal][lseqLocal], pitch 72 (conflict-free, 16B-aligned)
#pragma unroll
      for (int m = 0; m < 4; ++m) {
#pragma unroll
        for (int n = 0; n < 4; ++n) {
          const int colL = wc * 64 + n * 16 + lr;
#pragma unroll
          for (int rr = 0; rr < 2; ++rr) {
            const int r = nb + 2 * rr;
            const int rowL = wr * 64 + m * 16 + 4 * lg + r;  // parity nb
            lAB[colL * 72 + (rowL >> 1)] = f2bf(acc[m][n][r] + biasn[n]);
          }
        }
      }
      __syncthreads();
#pragma unroll
      for (int p = 0; p < 4; ++p) {
        const int c = p * 256 + tid;          // 0..1023
        const int colL = c >> 3, ls0 = (c & 7) * 8;
        const short8 v = *(const short8*)&lAB[colL * 72 + ls0];
        const int fullcol = nbase + colL;
        const int hd = fullcol >> 6, d = fullcol & 63;
        const int zz = nb * HEADS + hd;
        *(short8*)&Vo[((size_t)zz * DH + d) * L_SEQ + (mbase >> 1) + ls0] = v;
      }
      __syncthreads();
    }
    return;
  }

#pragma unroll
  for (int n = 0; n < 4; ++n) {
    const int col = nbase + wc * 64 + n * 16 + lr;
    const float bias = B[col];
#pragma unroll
    for (int m = 0; m < 4; ++m) {
#pragma unroll
      for (int r = 0; r < 4; ++r) {
        const int row = mbase + wr * 64 + m * 16 + 4 * lg + r;
        const float v = acc[m][n][r] + bias;
        if (FINAL) {
          Fo[(size_t)row * HID + col] = v;
        } else {
          const int lseq = row >> 1, nb = row & 1;
          const int z = nb * HEADS + (col >> 6), d = col & 63;
          if (zid == 0)
            Qo[((size_t)z * L_SEQ + lseq) * DH + d] = f2bf(v * 0.125f);
          else
            Ko[((size_t)z * L_SEQ + lseq) * DH + d] = f2bf(v);
        }
      }
    }
  }
}

// ---------------- block-sparse attention ----------------
// Middle WGs (bid < 32*62): one per (z, qb in [2,64)), 7 slots, write O.
// Head WGs (bid >= 32*62): split-K — one per (z, qb in {0,1}, split in [0,8)),
// 8 key blocks each; write unnormalized partial O + per-row m,l to ws.
__global__ __launch_bounds__(256)
void attn_sparse(const ushort* __restrict__ Q, const ushort* __restrict__ K,
                 const ushort* __restrict__ Vt, const int* __restrict__ rnd,
                 ushort* __restrict__ O,
                 float* __restrict__ Pp, float* __restrict__ Mp,
                 float* __restrict__ Lp) {
  const int bid = blockIdx.x;
  int z, qb, split = 0;
  bool head;
  if (bid < Z_DIM * 62) {
    z = bid / 62; qb = bid % 62 + 2; head = false;
  } else {
    const int t = bid - Z_DIM * 62;          // 0..511
    z = t >> 4; qb = (t >> 3) & 1; split = t & 7; head = true;
  }
  const int tid = threadIdx.x;
  const int w = tid >> 6, l = tid & 63;
  const int lr = l & 15, lg = l >> 4;

  __shared__ ushort Kl[64 * 64];
  __shared__ ushort Vl[64 * 64];
  __shared__ ushort Pl[4][16 * 64];

  const ushort* Qbase = Q + ((size_t)z * L_SEQ + qb * 64 + w * 16) * DH;
  const short8 aq0 = *(const short8*)(Qbase + lr * DH + lg * 8);
  const short8 aq1 = *(const short8*)(Qbase + lr * DH + 32 + lg * 8);

  float m[4], lsum[4];
  f32x4 accO[4];
#pragma unroll
  for (int r = 0; r < 4; ++r) { m[r] = -1e30f; lsum[r] = 0.f; }
#pragma unroll
  for (int t = 0; t < 4; ++t) accO[t] = (f32x4){0.f, 0.f, 0.f, 0.f};

  const int nslot = head ? 8 : 7;
  int sk[3] = {0, 0, 0}, sv[3] = {0, 0, 0}, rk0 = 0, rk1 = 0;
  if (!head) {
    const int i = qb - 2;
    rk0 = rnd[2 * i]; rk1 = rnd[2 * i + 1];
    if (qb < NBLK - 1) {
      sk[0] = qb - 1; sk[1] = qb; sk[2] = qb + 1;
      sv[0] = qb - 1; sv[1] = qb; sv[2] = qb + 1;
    } else {  // bottom row: K = {ZERO, 62, 63}, V = {62, 63, ZERO}
      sk[0] = -1; sk[1] = NBLK - 2; sk[2] = NBLK - 1;
      sv[0] = NBLK - 2; sv[1] = NBLK - 1; sv[2] = -1;
    }
  }

  for (int slot = 0; slot < nslot; ++slot) {
    int ki, vi;
    if (head) { ki = split * 8 + slot; vi = ki; }
    else if (slot < 2) { ki = slot; vi = slot; }
    else if (slot < 5) { ki = sk[slot - 2]; vi = sv[slot - 2]; }
    else { ki = (slot == 5) ? rk0 : rk1; vi = ki; }

    if (slot) __syncthreads();  // all waves done reading Kl/Vl
#pragma unroll
    for (int s = 0; s < 2; ++s) {
      const int chunk = s * 256 + tid;
      const int row = chunk >> 3, cc = chunk & 7;
      const int scc = cc ^ (row & 7);  // pre-swizzled global source
      if (ki >= 0)
        gload_lds16(K + ((size_t)z * L_SEQ + ki * 64 + row) * DH + scc * 8,
                    &Kl[(s * 256 + (tid & ~63)) * 8]);
      if (vi >= 0)
        gload_lds16(Vt + ((size_t)z * DH + row) * L_SEQ + vi * 64 + scc * 8,
                    &Vl[(s * 256 + (tid & ~63)) * 8]);
    }
    __syncthreads();

    // scores: S[q][key] for 16 q-rows x 64 keys
    f32x4 sc[4];
    if (ki >= 0) {
#pragma unroll
      for (int t = 0; t < 4; ++t) {
        const int r = t * 16 + lr;
        const short8 b0 = *(const short8*)&Kl[r * 64 + ((lg ^ (r & 7)) << 3)];
        const short8 b1 = *(const short8*)&Kl[r * 64 + (((4 + lg) ^ (r & 7)) << 3)];
        f32x4 zz = (f32x4){0.f, 0.f, 0.f, 0.f};
        sc[t] = __builtin_amdgcn_mfma_f32_16x16x32_bf16(aq0, b0, zz, 0, 0, 0);
        sc[t] = __builtin_amdgcn_mfma_f32_16x16x32_bf16(aq1, b1, sc[t], 0, 0, 0);
      }
    } else {
#pragma unroll
      for (int t = 0; t < 4; ++t) sc[t] = (f32x4){0.f, 0.f, 0.f, 0.f};
    }

    // online softmax (rows owned by 16-lane groups; reduce via shfl_xor)
#pragma unroll
    for (int r = 0; r < 4; ++r) {
      float sm = fmaxf(fmaxf(sc[0][r], sc[1][r]), fmaxf(sc[2][r], sc[3][r]));
      sm = fmaxf(sm, __shfl_xor(sm, 1));
      sm = fmaxf(sm, __shfl_xor(sm, 2));
      sm = fmaxf(sm, __shfl_xor(sm, 4));
      sm = fmaxf(sm, __shfl_xor(sm, 8));
      const float mn = fmaxf(m[r], sm);
      const float scale = __expf(m[r] - mn);
      m[r] = mn;
      lsum[r] *= scale;
#pragma unroll
      for (int t = 0; t < 4; ++t) accO[t][r] *= scale;
      float psum = 0.f;
#pragma unroll
      for (int t = 0; t < 4; ++t) {
        const float p = __expf(sc[t][r] - mn);
        sc[t][r] = p;
        psum += p;
      }
      lsum[r] += psum;
    }

    if (vi >= 0) {
      // P -> bf16 -> per-wave swizzled LDS, then read back as A-fragments
      ushort* P = &Pl[w][0];
#pragma unroll
      for (int t = 0; t < 4; ++t) {
#pragma unroll
        for (int r = 0; r < 4; ++r) {
          const int prow = 4 * lg + r, pcol = lr + 16 * t;
          P[prow * 64 + (((pcol >> 3) ^ (prow & 7)) << 3) + (pcol & 7)] = f2bf(sc[t][r]);
        }
      }
      const short8 ap0 = *(const short8*)&P[lr * 64 + ((lg ^ (lr & 7)) << 3)];
      const short8 ap1 = *(const short8*)&P[lr * 64 + (((4 + lg) ^ (lr & 7)) << 3)];
#pragma unroll
      for (int t = 0; t < 4; ++t) {
        const int r = t * 16 + lr;
        const short8 bv0 = *(const short8*)&Vl[r * 64 + ((lg ^ (r & 7)) << 3)];
        const short8 bv1 = *(const short8*)&Vl[r * 64 + (((4 + lg) ^ (r & 7)) << 3)];
        accO[t] = __builtin_amdgcn_mfma_f32_16x16x32_bf16(ap0, bv0, accO[t], 0, 0, 0);
        accO[t] = __builtin_amdgcn_mfma_f32_16x16x32_bf16(ap1, bv1, accO[t], 0, 0, 0);
      }
    }
  }

  // row sums across 16 lanes
#pragma unroll
  for (int r = 0; r < 4; ++r) {
    float s = lsum[r];
    s += __shfl_xor(s, 1);
    s += __shfl_xor(s, 2);
    s += __shfl_xor(s, 4);
    s += __shfl_xor(s, 8);
    lsum[r] = s;
  }

  if (!head) {
    const int nb = z >> 4, hd = z & 15;
#pragma unroll
    for (int t = 0; t < 4; ++t) {
#pragma unroll
      for (int r = 0; r < 4; ++r) {
        const int lseq = qb * 64 + w * 16 + 4 * lg + r;
        O[((size_t)lseq * NBATCH + nb) * HID + hd * 64 + lr + 16 * t] =
            f2bf(accO[t][r] / lsum[r]);
      }
    }
  } else {
    const int hbase = (qb * Z_DIM + z) * NSPLIT + split;
#pragma unroll
    for (int t = 0; t < 4; ++t) {
#pragma unroll
      for (int r = 0; r < 4; ++r) {
        const int row = w * 16 + 4 * lg + r;   // 0..63 within the q-block
        Pp[((size_t)hbase * 64 + row) * 64 + lr + 16 * t] = accO[t][r];
      }
    }
    if (lr == 0) {
#pragma unroll
      for (int r = 0; r < 4; ++r) {
        const int row = w * 16 + 4 * lg + r;
        Mp[hbase * 64 + row] = m[r];
        Lp[hbase * 64 + row] = lsum[r];
      }
    }
  }
}

// ---------------- combine head split-K partials ----------------
// grid: 64 WGs = (z, qb); thread owns (row, 16 cols).
__global__ __launch_bounds__(256)
void head_reduce(const float* __restrict__ Pp, const float* __restrict__ Mp,
                 const float* __restrict__ Lp, ushort* __restrict__ O) {
  const int z = blockIdx.x >> 1, qb = blockIdx.x & 1;
  const int tid = threadIdx.x;
  const int row = tid >> 2, cg = tid & 3;
  const int base = (qb * Z_DIM + z) * NSPLIT;

  float mm[NSPLIT], wgt[NSPLIT];
  float mx = -1e30f;
#pragma unroll
  for (int s = 0; s < NSPLIT; ++s) {
    mm[s] = Mp[(base + s) * 64 + row];
    mx = fmaxf(mx, mm[s]);
  }
  float denom = 0.f;
#pragma unroll
  for (int s = 0; s < NSPLIT; ++s) {
    wgt[s] = __expf(mm[s] - mx);
    denom += Lp[(base + s) * 64 + row] * wgt[s];
  }
  const float inv = 1.f / denom;

  const int nb = z >> 4, hd = z & 15;
  const int lseq = qb * 64 + row;
#pragma unroll
  for (int c = 0; c < 16; ++c) {
    const int col = cg * 16 + c;
    float acc = 0.f;
#pragma unroll
    for (int s = 0; s < NSPLIT; ++s)
      acc += Pp[((size_t)(base + s) * 64 + row) * 64 + col] * wgt[s];
    O[((size_t)lseq * NBATCH + nb) * HID + hd * 64 + col] = f2bf(acc * inv);
  }
}

extern "C" void kernel_launch(void* const* d_in, const int* in_sizes, int n_in,
                              void* d_out, int out_size, void* d_ws, size_t ws_size,
                              hipStream_t stream) {
  (void)in_sizes; (void)n_in; (void)out_size; (void)ws_size;
  const float* query    = (const float*)d_in[0];
  const float* q_proj   = (const float*)d_in[1];
  const float* q_bias   = (const float*)d_in[2];
  const float* k_proj   = (const float*)d_in[3];
  const float* k_bias   = (const float*)d_in[4];
  const float* v_proj   = (const float*)d_in[5];
  const float* v_bias   = (const float*)d_in[6];
  const float* out_proj = (const float*)d_in[7];
  const float* out_bias = (const float*)d_in[8];
  const int*   rnd      = (const int*)d_in[9];

  ushort* Xb  = (ushort*)d_ws;                         // [8192][1024] bf16
  ushort* Wq  = Xb + (size_t)NROWS * HID;
  ushort* Wk  = Wq + (size_t)HID * HID;
  ushort* Wv  = Wk + (size_t)HID * HID;
  ushort* Wo  = Wv + (size_t)HID * HID;
  ushort* Qb  = Wo + (size_t)HID * HID;                // [Z][L][64]
  ushort* Kb  = Qb + (size_t)Z_DIM * L_SEQ * DH;       // [Z][L][64]
  ushort* Vtb = Kb + (size_t)Z_DIM * L_SEQ * DH;       // [Z][64][L]
  float*  Pp  = (float*)(Vtb + (size_t)Z_DIM * DH * L_SEQ);  // head partials
  float*  Mp  = Pp + (size_t)2 * Z_DIM * NSPLIT * 64 * 64;
  float*  Lp  = Mp + (size_t)2 * Z_DIM * NSPLIT * 64;
  ushort* Ob  = Xb;  // alias: X dead after QKV GEMM, O written by attn
  float*  Fo  = (float*)d_out;

  cvt_f32_bf16<<<2048, 256, 0, stream>>>(query, Xb, NROWS * HID / 4);
  cvt_f32_bf16<<<1024, 256, 0, stream>>>(q_proj, Wq, HID * HID / 4);
  cvt_f32_bf16<<<1024, 256, 0, stream>>>(k_proj, Wk, HID * HID / 4);
  cvt_f32_bf16<<<1024, 256, 0, stream>>>(v_proj, Wv, HID * HID / 4);
  cvt_f32_bf16<<<1024, 256, 0, stream>>>(out_proj, Wo, HID * HID / 4);

  gemm_bt<0><<<dim3(8, 64, 3), 256, 0, stream>>>(
      Xb, Wq, Wk, Wv, q_bias, k_bias, v_bias, Qb, Kb, Vtb, nullptr);

  attn_sparse<<<Z_DIM * 62 + 2 * Z_DIM * NSPLIT, 256, 0, stream>>>(
      Qb, Kb, Vtb, rnd, Ob, Pp, Mp, Lp);

  head_reduce<<<2 * Z_DIM, 256, 0, stream>>>(Pp, Mp, Lp, Ob);

  gemm_bt<1><<<dim3(8, 64, 1), 256, 0, stream>>>(
      Ob, Wo, nullptr, nullptr, out_bias, nullptr, nullptr,
      nullptr, nullptr, nullptr, Fo);
}

// Round 4
// 188.086 us; speedup vs baseline: 1.2473x; 1.2473x over previous
//
#include <hip/hip_runtime.h>
#include <stdint.h>

#define L_SEQ 4096
#define NBATCH 2
#define HID 1024
#define HEADS 16
#define DH 64
#define Z_DIM 32
#define NBLK 64
#define NROWS 8192  // L_SEQ * NBATCH
#define NSPLIT 8    // head split-K factor (8 kblocks per split)

typedef float f32x4 __attribute__((ext_vector_type(4)));
typedef short short8 __attribute__((ext_vector_type(8)));

typedef const uint32_t __attribute__((address_space(1))) *gas_ptr;
typedef uint32_t __attribute__((address_space(3))) *las_ptr;

__device__ __forceinline__ ushort f2bf(float f) {
  uint32_t u = __float_as_uint(f);
  uint32_t r = (u + 0x7FFFu + ((u >> 16) & 1u)) >> 16;  // RNE
  return (ushort)r;
}

__device__ __forceinline__ void gload_lds16(const void* g, void* l) {
  __builtin_amdgcn_global_load_lds((gas_ptr)g, (las_ptr)l, 16, 0, 0);
}

// ---------------- f32 -> bf16 conversion ----------------
__global__ void cvt_f32_bf16(const float* __restrict__ src, ushort* __restrict__ dst, int n4) {
  int i = blockIdx.x * blockDim.x + threadIdx.x;
  const int stride = gridDim.x * blockDim.x;
  for (; i < n4; i += stride) {
    float4 v = ((const float4*)src)[i];
    ushort4 o;
    o.x = f2bf(v.x); o.y = f2bf(v.y); o.z = f2bf(v.z); o.w = f2bf(v.w);
    ((ushort4*)dst)[i] = o;
  }
}

// ---------------- bf16 NT GEMM: C = X @ W^T + bias ----------------
// 128x128 tile, BK=32 (low VGPR -> 6 WG/CU), 4 waves (2x2), 16x16x32 MFMA,
// global_load_lds staging with loop-invariant XOR swizzle (row&3 == lr&3).
// 1D grid with bijective XCD swizzle for L2 locality.
// FINAL=0: zid selects Q/K/V; ALL epilogues go through LDS transpose staging
//          and write coalesced 16B bf16 stores (Q/K -> [z][l][d], V -> [z][d][l]).
// FINAL=1: direct f32 row-major [8192][1024] stores (d_out).
template <int FINAL>
__global__ __launch_bounds__(256)
void gemm_bt(const ushort* __restrict__ X,
             const ushort* __restrict__ W0, const ushort* __restrict__ W1,
             const ushort* __restrict__ W2,
             const float* __restrict__ b0, const float* __restrict__ b1,
             const float* __restrict__ b2,
             ushort* __restrict__ Qo, ushort* __restrict__ Ko,
             ushort* __restrict__ Vo, float* __restrict__ Fo) {
  const int tid = threadIdx.x;
  const int w = tid >> 6, l = tid & 63;
  const int lr = l & 15, lg = l >> 4;
  const int wr = w >> 1, wc = w & 1;

  // XCD-aware bijective block swizzle (total % 8 == 0)
  const int total = FINAL ? 512 : 1536;
  const int per = total >> 3;
  const int f0 = blockIdx.x;
  const int nf = (f0 & 7) * per + (f0 >> 3);
  const int bx = nf & 7;
  const int by = (nf >> 3) & 63;
  const int zid = FINAL ? 0 : (nf >> 9);
  const int mbase = by * 128;
  const int nbase = bx * 128;

  const ushort* W = FINAL ? W0 : (zid == 0 ? W0 : (zid == 1 ? W1 : W2));
  const float*  B = FINAL ? b0 : (zid == 0 ? b0 : (zid == 1 ? b1 : b2));

  __shared__ ushort lds[8192];   // 16 KiB: lA | lB in main loop; staging in epilogue
  ushort* lA = lds;
  ushort* lB = lds + 4096;

  // loop-invariant swizzled k-chunk offset (shorts) within a 32-short row
  const int kch = (lg ^ (lr & 3)) << 3;

  f32x4 acc[4][4];
#pragma unroll
  for (int m = 0; m < 4; ++m)
#pragma unroll
    for (int n = 0; n < 4; ++n) acc[m][n] = (f32x4){0.f, 0.f, 0.f, 0.f};

  for (int k0 = 0; k0 < HID; k0 += 32) {
#pragma unroll
    for (int s = 0; s < 2; ++s) {
      const int chunk = s * 256 + tid;         // 0..511, 16B chunks
      const int row = chunk >> 2, cc = chunk & 3;
      const int scc = cc ^ (row & 3);          // pre-swizzled global source
      void* dstA = &lA[(s * 256 + (tid & ~63)) * 8];
      void* dstB = &lB[(s * 256 + (tid & ~63)) * 8];
      gload_lds16(X + (size_t)(mbase + row) * HID + k0 + scc * 8, dstA);
      gload_lds16(W + (size_t)(nbase + row) * HID + k0 + scc * 8, dstB);
    }
    __syncthreads();
    short8 af[4], bfr[4];
#pragma unroll
    for (int m = 0; m < 4; ++m)
      af[m] = *(const short8*)&lA[(wr * 64 + m * 16 + lr) * 32 + kch];
#pragma unroll
    for (int n = 0; n < 4; ++n)
      bfr[n] = *(const short8*)&lB[(wc * 64 + n * 16 + lr) * 32 + kch];
#pragma unroll
    for (int m = 0; m < 4; ++m)
#pragma unroll
      for (int n = 0; n < 4; ++n)
        acc[m][n] = __builtin_amdgcn_mfma_f32_16x16x32_bf16(af[m], bfr[n], acc[m][n], 0, 0, 0);
    __syncthreads();
  }

  if (FINAL) {
#pragma unroll
    for (int n = 0; n < 4; ++n) {
      const int col = nbase + wc * 64 + n * 16 + lr;
      const float bias = B[col];
#pragma unroll
      for (int m = 0; m < 4; ++m)
#pragma unroll
        for (int r = 0; r < 4; ++r) {
          const int row = mbase + wr * 64 + m * 16 + 4 * lg + r;
          Fo[(size_t)row * HID + col] = acc[m][n][r] + bias;
        }
    }
    return;
  }

  float biasn[4];
#pragma unroll
  for (int n = 0; n < 4; ++n) biasn[n] = B[nbase + wc * 64 + n * 16 + lr];

  if (zid == 2) {
    // ---- V: LDS transpose -> coalesced Vt[z][d][lseq] (16B stores) ----
#pragma unroll
    for (int nb2 = 0; nb2 < 2; ++nb2) {
#pragma unroll
      for (int ch = 0; ch < 2; ++ch) {
        __syncthreads();
        if (wc == ch) {
#pragma unroll
          for (int m = 0; m < 4; ++m)
#pragma unroll
            for (int n = 0; n < 4; ++n)
#pragma unroll
              for (int rr = 0; rr < 2; ++rr) {
                const int r = nb2 + 2 * rr;
                lds[(n * 16 + lr) * 72 + wr * 32 + m * 8 + 2 * lg + rr] =
                    f2bf(acc[m][n][r] + biasn[n]);
              }
        }
        __syncthreads();
        const int zz = nb2 * HEADS + (nbase >> 6) + ch;
#pragma unroll
        for (int it = 0; it < 2; ++it) {
          const int c = it * 256 + tid;          // 0..511
          const int colI = c >> 3, ls0 = (c & 7) * 8;
          const short8 v = *(const short8*)&lds[colI * 72 + ls0];
          *(short8*)&Vo[((size_t)zz * DH + colI) * L_SEQ + (mbase >> 1) + ls0] = v;
        }
      }
    }
  } else {
    // ---- Q/K: LDS stage -> coalesced Out[z][lseq][d] (16B stores) ----
    ushort* Out = (zid == 0) ? Qo : Ko;
    const float sc = (zid == 0) ? 0.125f : 1.f;
#pragma unroll
    for (int nbp = 0; nbp < 2; ++nbp) {
#pragma unroll
      for (int hh = 0; hh < 2; ++hh) {
        __syncthreads();
        if (wc == hh) {
#pragma unroll
          for (int m = 0; m < 4; ++m)
#pragma unroll
            for (int n = 0; n < 4; ++n)
#pragma unroll
              for (int rr = 0; rr < 2; ++rr) {
                const int r = nbp + 2 * rr;
                lds[(wr * 32 + m * 8 + 2 * lg + rr) * 72 + n * 16 + lr] =
                    f2bf((acc[m][n][r] + biasn[n]) * sc);
              }
        }
        __syncthreads();
        const int zz = nbp * HEADS + (nbase >> 6) + hh;
#pragma unroll
        for (int it = 0; it < 2; ++it) {
          const int c = it * 256 + tid;          // 0..511
          const int lr2 = c >> 3, cc8 = c & 7;
          const short8 v = *(const short8*)&lds[lr2 * 72 + cc8 * 8];
          *(short8*)&Out[((size_t)zz * L_SEQ + (mbase >> 1) + lr2) * DH + cc8 * 8] = v;
        }
      }
    }
  }
}

// ---------------- block-sparse attention ----------------
// Middle WGs (bid < 32*62): one per (z, qb in [2,64)), 7 slots, write O.
// Head WGs (bid >= 32*62): split-K — one per (z, qb in {0,1}, split in [0,8)),
// 8 key blocks each; write unnormalized partial O + per-row m,l to ws.
__global__ __launch_bounds__(256)
void attn_sparse(const ushort* __restrict__ Q, const ushort* __restrict__ K,
                 const ushort* __restrict__ Vt, const int* __restrict__ rnd,
                 ushort* __restrict__ O,
                 float* __restrict__ Pp, float* __restrict__ Mp,
                 float* __restrict__ Lp) {
  const int bid = blockIdx.x;
  int z, qb, split = 0;
  bool head;
  if (bid < Z_DIM * 62) {
    z = bid / 62; qb = bid % 62 + 2; head = false;
  } else {
    const int t = bid - Z_DIM * 62;          // 0..511
    z = t >> 4; qb = (t >> 3) & 1; split = t & 7; head = true;
  }
  const int tid = threadIdx.x;
  const int w = tid >> 6, l = tid & 63;
  const int lr = l & 15, lg = l >> 4;

  __shared__ ushort Kl[64 * 64];
  __shared__ ushort Vl[64 * 64];
  __shared__ ushort Pl[4][16 * 64];

  const ushort* Qbase = Q + ((size_t)z * L_SEQ + qb * 64 + w * 16) * DH;
  const short8 aq0 = *(const short8*)(Qbase + lr * DH + lg * 8);
  const short8 aq1 = *(const short8*)(Qbase + lr * DH + 32 + lg * 8);

  float m[4], lsum[4];
  f32x4 accO[4];
#pragma unroll
  for (int r = 0; r < 4; ++r) { m[r] = -1e30f; lsum[r] = 0.f; }
#pragma unroll
  for (int t = 0; t < 4; ++t) accO[t] = (f32x4){0.f, 0.f, 0.f, 0.f};

  const int nslot = head ? 8 : 7;
  int sk[3] = {0, 0, 0}, sv[3] = {0, 0, 0}, rk0 = 0, rk1 = 0;
  if (!head) {
    const int i = qb - 2;
    rk0 = rnd[2 * i]; rk1 = rnd[2 * i + 1];
    if (qb < NBLK - 1) {
      sk[0] = qb - 1; sk[1] = qb; sk[2] = qb + 1;
      sv[0] = qb - 1; sv[1] = qb; sv[2] = qb + 1;
    } else {  // bottom row: K = {ZERO, 62, 63}, V = {62, 63, ZERO}
      sk[0] = -1; sk[1] = NBLK - 2; sk[2] = NBLK - 1;
      sv[0] = NBLK - 2; sv[1] = NBLK - 1; sv[2] = -1;
    }
  }

  for (int slot = 0; slot < nslot; ++slot) {
    int ki, vi;
    if (head) { ki = split * 8 + slot; vi = ki; }
    else if (slot < 2) { ki = slot; vi = slot; }
    else if (slot < 5) { ki = sk[slot - 2]; vi = sv[slot - 2]; }
    else { ki = (slot == 5) ? rk0 : rk1; vi = ki; }

    if (slot) __syncthreads();  // all waves done reading Kl/Vl
#pragma unroll
    for (int s = 0; s < 2; ++s) {
      const int chunk = s * 256 + tid;
      const int row = chunk >> 3, cc = chunk & 7;
      const int scc = cc ^ (row & 7);  // pre-swizzled global source
      if (ki >= 0)
        gload_lds16(K + ((size_t)z * L_SEQ + ki * 64 + row) * DH + scc * 8,
                    &Kl[(s * 256 + (tid & ~63)) * 8]);
      if (vi >= 0)
        gload_lds16(Vt + ((size_t)z * DH + row) * L_SEQ + vi * 64 + scc * 8,
                    &Vl[(s * 256 + (tid & ~63)) * 8]);
    }
    __syncthreads();

    // scores: S[q][key] for 16 q-rows x 64 keys
    f32x4 sc[4];
    if (ki >= 0) {
#pragma unroll
      for (int t = 0; t < 4; ++t) {
        const int r = t * 16 + lr;
        const short8 b0 = *(const short8*)&Kl[r * 64 + ((lg ^ (r & 7)) << 3)];
        const short8 b1 = *(const short8*)&Kl[r * 64 + (((4 + lg) ^ (r & 7)) << 3)];
        f32x4 zz = (f32x4){0.f, 0.f, 0.f, 0.f};
        sc[t] = __builtin_amdgcn_mfma_f32_16x16x32_bf16(aq0, b0, zz, 0, 0, 0);
        sc[t] = __builtin_amdgcn_mfma_f32_16x16x32_bf16(aq1, b1, sc[t], 0, 0, 0);
      }
    } else {
#pragma unroll
      for (int t = 0; t < 4; ++t) sc[t] = (f32x4){0.f, 0.f, 0.f, 0.f};
    }

    // online softmax (rows owned by 16-lane groups; reduce via shfl_xor)
#pragma unroll
    for (int r = 0; r < 4; ++r) {
      float sm = fmaxf(fmaxf(sc[0][r], sc[1][r]), fmaxf(sc[2][r], sc[3][r]));
      sm = fmaxf(sm, __shfl_xor(sm, 1));
      sm = fmaxf(sm, __shfl_xor(sm, 2));
      sm = fmaxf(sm, __shfl_xor(sm, 4));
      sm = fmaxf(sm, __shfl_xor(sm, 8));
      const float mn = fmaxf(m[r], sm);
      const float scale = __expf(m[r] - mn);
      m[r] = mn;
      lsum[r] *= scale;
#pragma unroll
      for (int t = 0; t < 4; ++t) accO[t][r] *= scale;
      float psum = 0.f;
#pragma unroll
      for (int t = 0; t < 4; ++t) {
        const float p = __expf(sc[t][r] - mn);
        sc[t][r] = p;
        psum += p;
      }
      lsum[r] += psum;
    }

    if (vi >= 0) {
      // P -> bf16 -> per-wave swizzled LDS, then read back as A-fragments
      ushort* P = &Pl[w][0];
#pragma unroll
      for (int t = 0; t < 4; ++t) {
#pragma unroll
        for (int r = 0; r < 4; ++r) {
          const int prow = 4 * lg + r, pcol = lr + 16 * t;
          P[prow * 64 + (((pcol >> 3) ^ (prow & 7)) << 3) + (pcol & 7)] = f2bf(sc[t][r]);
        }
      }
      const short8 ap0 = *(const short8*)&P[lr * 64 + ((lg ^ (lr & 7)) << 3)];
      const short8 ap1 = *(const short8*)&P[lr * 64 + (((4 + lg) ^ (lr & 7)) << 3)];
#pragma unroll
      for (int t = 0; t < 4; ++t) {
        const int r = t * 16 + lr;
        const short8 bv0 = *(const short8*)&Vl[r * 64 + ((lg ^ (r & 7)) << 3)];
        const short8 bv1 = *(const short8*)&Vl[r * 64 + (((4 + lg) ^ (r & 7)) << 3)];
        accO[t] = __builtin_amdgcn_mfma_f32_16x16x32_bf16(ap0, bv0, accO[t], 0, 0, 0);
        accO[t] = __builtin_amdgcn_mfma_f32_16x16x32_bf16(ap1, bv1, accO[t], 0, 0, 0);
      }
    }
  }

  // row sums across 16 lanes
#pragma unroll
  for (int r = 0; r < 4; ++r) {
    float s = lsum[r];
    s += __shfl_xor(s, 1);
    s += __shfl_xor(s, 2);
    s += __shfl_xor(s, 4);
    s += __shfl_xor(s, 8);
    lsum[r] = s;
  }

  if (!head) {
    const int nb = z >> 4, hd = z & 15;
#pragma unroll
    for (int t = 0; t < 4; ++t) {
#pragma unroll
      for (int r = 0; r < 4; ++r) {
        const int lseq = qb * 64 + w * 16 + 4 * lg + r;
        O[((size_t)lseq * NBATCH + nb) * HID + hd * 64 + lr + 16 * t] =
            f2bf(accO[t][r] / lsum[r]);
      }
    }
  } else {
    const int hbase = (qb * Z_DIM + z) * NSPLIT + split;
#pragma unroll
    for (int t = 0; t < 4; ++t) {
#pragma unroll
      for (int r = 0; r < 4; ++r) {
        const int row = w * 16 + 4 * lg + r;   // 0..63 within the q-block
        Pp[((size_t)hbase * 64 + row) * 64 + lr + 16 * t] = accO[t][r];
      }
    }
    if (lr == 0) {
#pragma unroll
      for (int r = 0; r < 4; ++r) {
        const int row = w * 16 + 4 * lg + r;
        Mp[hbase * 64 + row] = m[r];
        Lp[hbase * 64 + row] = lsum[r];
      }
    }
  }
}

// ---------------- combine head split-K partials ----------------
// grid: 64 WGs = (z, qb); thread owns (row, 16 cols).
__global__ __launch_bounds__(256)
void head_reduce(const float* __restrict__ Pp, const float* __restrict__ Mp,
                 const float* __restrict__ Lp, ushort* __restrict__ O) {
  const int z = blockIdx.x >> 1, qb = blockIdx.x & 1;
  const int tid = threadIdx.x;
  const int row = tid >> 2, cg = tid & 3;
  const int base = (qb * Z_DIM + z) * NSPLIT;

  float mm[NSPLIT], wgt[NSPLIT];
  float mx = -1e30f;
#pragma unroll
  for (int s = 0; s < NSPLIT; ++s) {
    mm[s] = Mp[(base + s) * 64 + row];
    mx = fmaxf(mx, mm[s]);
  }
  float denom = 0.f;
#pragma unroll
  for (int s = 0; s < NSPLIT; ++s) {
    wgt[s] = __expf(mm[s] - mx);
    denom += Lp[(base + s) * 64 + row] * wgt[s];
  }
  const float inv = 1.f / denom;

  const int nb = z >> 4, hd = z & 15;
  const int lseq = qb * 64 + row;
#pragma unroll
  for (int c = 0; c < 16; ++c) {
    const int col = cg * 16 + c;
    float acc = 0.f;
#pragma unroll
    for (int s = 0; s < NSPLIT; ++s)
      acc += Pp[((size_t)(base + s) * 64 + row) * 64 + col] * wgt[s];
    O[((size_t)lseq * NBATCH + nb) * HID + hd * 64 + col] = f2bf(acc * inv);
  }
}

extern "C" void kernel_launch(void* const* d_in, const int* in_sizes, int n_in,
                              void* d_out, int out_size, void* d_ws, size_t ws_size,
                              hipStream_t stream) {
  (void)in_sizes; (void)n_in; (void)out_size; (void)ws_size;
  const float* query    = (const float*)d_in[0];
  const float* q_proj   = (const float*)d_in[1];
  const float* q_bias   = (const float*)d_in[2];
  const float* k_proj   = (const float*)d_in[3];
  const float* k_bias   = (const float*)d_in[4];
  const float* v_proj   = (const float*)d_in[5];
  const float* v_bias   = (const float*)d_in[6];
  const float* out_proj = (const float*)d_in[7];
  const float* out_bias = (const float*)d_in[8];
  const int*   rnd      = (const int*)d_in[9];

  ushort* Xb  = (ushort*)d_ws;                         // [8192][1024] bf16
  ushort* Wq  = Xb + (size_t)NROWS * HID;
  ushort* Wk  = Wq + (size_t)HID * HID;
  ushort* Wv  = Wk + (size_t)HID * HID;
  ushort* Wo  = Wv + (size_t)HID * HID;
  ushort* Qb  = Wo + (size_t)HID * HID;                // [Z][L][64]
  ushort* Kb  = Qb + (size_t)Z_DIM * L_SEQ * DH;       // [Z][L][64]
  ushort* Vtb = Kb + (size_t)Z_DIM * L_SEQ * DH;       // [Z][64][L]
  float*  Pp  = (float*)(Vtb + (size_t)Z_DIM * DH * L_SEQ);  // head partials
  float*  Mp  = Pp + (size_t)2 * Z_DIM * NSPLIT * 64 * 64;
  float*  Lp  = Mp + (size_t)2 * Z_DIM * NSPLIT * 64;
  ushort* Ob  = Xb;  // alias: X dead after QKV GEMM, O written by attn
  float*  Fo  = (float*)d_out;

  cvt_f32_bf16<<<2048, 256, 0, stream>>>(query, Xb, NROWS * HID / 4);
  cvt_f32_bf16<<<1024, 256, 0, stream>>>(q_proj, Wq, HID * HID / 4);
  cvt_f32_bf16<<<1024, 256, 0, stream>>>(k_proj, Wk, HID * HID / 4);
  cvt_f32_bf16<<<1024, 256, 0, stream>>>(v_proj, Wv, HID * HID / 4);
  cvt_f32_bf16<<<1024, 256, 0, stream>>>(out_proj, Wo, HID * HID / 4);

  gemm_bt<0><<<1536, 256, 0, stream>>>(
      Xb, Wq, Wk, Wv, q_bias, k_bias, v_bias, Qb, Kb, Vtb, nullptr);

  attn_sparse<<<Z_DIM * 62 + 2 * Z_DIM * NSPLIT, 256, 0, stream>>>(
      Qb, Kb, Vtb, rnd, Ob, Pp, Mp, Lp);

  head_reduce<<<2 * Z_DIM, 256, 0, stream>>>(Pp, Mp, Lp, Ob);

  gemm_bt<1><<<512, 256, 0, stream>>>(
      Ob, Wo, nullptr, nullptr, out_bias, nullptr, nullptr,
      nullptr, nullptr, nullptr, Fo);
}

// Round 5
// 172.389 us; speedup vs baseline: 1.3608x; 1.0911x over previous
//
#include <hip/hip_runtime.h>
#include <stdint.h>

#define L_SEQ 4096
#define NBATCH 2
#define HID 1024
#define HEADS 16
#define DH 64
#define Z_DIM 32
#define NBLK 64
#define NROWS 8192  // L_SEQ * NBATCH
#define NSPLIT 8    // head split-K factor (8 kblocks per split)

typedef float f32x4 __attribute__((ext_vector_type(4)));
typedef short short8 __attribute__((ext_vector_type(8)));

typedef const uint32_t __attribute__((address_space(1))) *gas_ptr;
typedef uint32_t __attribute__((address_space(3))) *las_ptr;

__device__ __forceinline__ ushort f2bf(float f) {
  uint32_t u = __float_as_uint(f);
  uint32_t r = (u + 0x7FFFu + ((u >> 16) & 1u)) >> 16;  // RNE
  return (ushort)r;
}

__device__ __forceinline__ void gload_lds16(const void* g, void* l) {
  __builtin_amdgcn_global_load_lds((gas_ptr)g, (las_ptr)l, 16, 0, 0);
}

// ---------------- fused f32 -> bf16 conversion (query + 4 weights) --------
__global__ __launch_bounds__(256)
void cvt_multi(const float* __restrict__ s0, ushort* __restrict__ d0,
               const float* __restrict__ s1, ushort* __restrict__ d1,
               const float* __restrict__ s2, ushort* __restrict__ d2,
               const float* __restrict__ s3, ushort* __restrict__ d3,
               const float* __restrict__ s4, ushort* __restrict__ d4) {
  const int i = blockIdx.x * blockDim.x + threadIdx.x;
  const int NQ = NROWS * HID / 4;          // 2097152 float4s
  const float4* src; ushort4* dst; int off;
  if (i < NQ) {
    src = (const float4*)s0; dst = (ushort4*)d0; off = i;
  } else {
    const int j = i - NQ;
    const int r = j >> 18;                  // HID*HID/4 = 2^18 per weight
    off = j & ((1 << 18) - 1);
    src = (const float4*)(r == 0 ? s1 : r == 1 ? s2 : r == 2 ? s3 : s4);
    dst = (ushort4*)(r == 0 ? d1 : r == 1 ? d2 : r == 2 ? d3 : d4);
  }
  float4 v = src[off];
  ushort4 o;
  o.x = f2bf(v.x); o.y = f2bf(v.y); o.z = f2bf(v.z); o.w = f2bf(v.w);
  dst[off] = o;
}

// ---------------- bf16 NT GEMM: C = X @ W^T + bias ----------------
// 128x128 tile, BK=32, 4 waves (2x2), 16x16x32 MFMA.
// Depth-2 software pipeline: 2 LDS buffers, counted vmcnt(4), raw barriers
// (T3/T4 minimum). 2-way-free XOR swizzle c ^= (row>>1)&3 on 16B chunks.
// 1D grid with bijective XCD swizzle.
// FINAL=0: zid selects Q/K/V; epilogues via LDS transpose staging, coalesced
//          16B bf16 stores (Q/K -> [z][l][d], V -> [z][d][l]).
// FINAL=1: direct f32 row-major [8192][1024] stores (d_out).
template <int FINAL>
__global__ __launch_bounds__(256)
void gemm_bt(const ushort* __restrict__ X,
             const ushort* __restrict__ W0, const ushort* __restrict__ W1,
             const ushort* __restrict__ W2,
             const float* __restrict__ b0, const float* __restrict__ b1,
             const float* __restrict__ b2,
             ushort* __restrict__ Qo, ushort* __restrict__ Ko,
             ushort* __restrict__ Vo, float* __restrict__ Fo) {
  const int tid = threadIdx.x;
  const int w = tid >> 6, l = tid & 63;
  const int lr = l & 15, lg = l >> 4;
  const int wr = w >> 1, wc = w & 1;

  // XCD-aware bijective block swizzle (total % 8 == 0)
  const int total = FINAL ? 512 : 1536;
  const int per = total >> 3;
  const int f0 = blockIdx.x;
  const int nf = (f0 & 7) * per + (f0 >> 3);
  const int bx = nf & 7;
  const int by = (nf >> 3) & 63;
  const int zid = FINAL ? 0 : (nf >> 9);
  const int mbase = by * 128;
  const int nbase = bx * 128;

  const ushort* W = FINAL ? W0 : (zid == 0 ? W0 : (zid == 1 ? W1 : W2));
  const float*  B = FINAL ? b0 : (zid == 0 ? b0 : (zid == 1 ? b1 : b2));

  __shared__ ushort lds[2][8192];  // 32 KiB: per buf, lA | lB (4096 each)

  // loop-invariant swizzled k-chunk offset (shorts) within a 32-short row
  const int kch = (lg ^ ((lr >> 1) & 3)) << 3;

  f32x4 acc[4][4];
#pragma unroll
  for (int m = 0; m < 4; ++m)
#pragma unroll
    for (int n = 0; n < 4; ++n) acc[m][n] = (f32x4){0.f, 0.f, 0.f, 0.f};

  auto stage = [&](int k0, int buf) {
#pragma unroll
    for (int s = 0; s < 2; ++s) {
      const int chunk = s * 256 + tid;        // 0..511, 16B chunks
      const int row = chunk >> 2, cc = chunk & 3;
      const int scc = cc ^ ((row >> 1) & 3);  // pre-swizzled global source
      gload_lds16(X + (size_t)(mbase + row) * HID + k0 + scc * 8,
                  &lds[buf][(s * 256 + (tid & ~63)) * 8]);
      gload_lds16(W + (size_t)(nbase + row) * HID + k0 + scc * 8,
                  &lds[buf][4096 + (s * 256 + (tid & ~63)) * 8]);
    }
  };

  auto compute_tile = [&](const ushort* lA, const ushort* lB) {
    short8 af[4], bfr[4];
#pragma unroll
    for (int m = 0; m < 4; ++m)
      af[m] = *(const short8*)&lA[(wr * 64 + m * 16 + lr) * 32 + kch];
#pragma unroll
    for (int n = 0; n < 4; ++n)
      bfr[n] = *(const short8*)&lB[(wc * 64 + n * 16 + lr) * 32 + kch];
#pragma unroll
    for (int m = 0; m < 4; ++m)
#pragma unroll
      for (int n = 0; n < 4; ++n)
        acc[m][n] = __builtin_amdgcn_mfma_f32_16x16x32_bf16(af[m], bfr[n], acc[m][n], 0, 0, 0);
  };

  // ---- depth-2 pipelined K-loop (32 tiles of BK=32) ----
  stage(0, 0);
  stage(32, 1);
  for (int t = 0; t < 32; ++t) {
    if (t < 30) { asm volatile("s_waitcnt vmcnt(4)" ::: "memory"); }
    else        { asm volatile("s_waitcnt vmcnt(0)" ::: "memory"); }
    __builtin_amdgcn_s_barrier();           // tile t fully in LDS (all waves)
    __builtin_amdgcn_sched_barrier(0);
    compute_tile(&lds[t & 1][0], &lds[t & 1][4096]);
    __builtin_amdgcn_sched_barrier(0);
    asm volatile("s_waitcnt lgkmcnt(0)" ::: "memory");
    __builtin_amdgcn_s_barrier();           // all waves done reading buf t&1
    if (t < 30) stage((t + 2) * 32, t & 1); // overwrite freed buffer
  }

  if (FINAL) {
#pragma unroll
    for (int n = 0; n < 4; ++n) {
      const int col = nbase + wc * 64 + n * 16 + lr;
      const float bias = B[col];
#pragma unroll
      for (int m = 0; m < 4; ++m)
#pragma unroll
        for (int r = 0; r < 4; ++r) {
          const int row = mbase + wr * 64 + m * 16 + 4 * lg + r;
          Fo[(size_t)row * HID + col] = acc[m][n][r] + bias;
        }
    }
    return;
  }

  float biasn[4];
#pragma unroll
  for (int n = 0; n < 4; ++n) biasn[n] = B[nbase + wc * 64 + n * 16 + lr];
  ushort* st = &lds[0][0];

  if (zid == 2) {
    // ---- V: LDS transpose -> coalesced Vt[z][d][lseq] (16B stores) ----
#pragma unroll
    for (int nb2 = 0; nb2 < 2; ++nb2) {
#pragma unroll
      for (int ch = 0; ch < 2; ++ch) {
        __syncthreads();
        if (wc == ch) {
#pragma unroll
          for (int m = 0; m < 4; ++m)
#pragma unroll
            for (int n = 0; n < 4; ++n)
#pragma unroll
              for (int rr = 0; rr < 2; ++rr) {
                const int r = nb2 + 2 * rr;
                st[(n * 16 + lr) * 72 + wr * 32 + m * 8 + 2 * lg + rr] =
                    f2bf(acc[m][n][r] + biasn[n]);
              }
        }
        __syncthreads();
        const int zz = nb2 * HEADS + (nbase >> 6) + ch;
#pragma unroll
        for (int it = 0; it < 2; ++it) {
          const int c = it * 256 + tid;          // 0..511
          const int colI = c >> 3, ls0 = (c & 7) * 8;
          const short8 v = *(const short8*)&st[colI * 72 + ls0];
          *(short8*)&Vo[((size_t)zz * DH + colI) * L_SEQ + (mbase >> 1) + ls0] = v;
        }
      }
    }
  } else {
    // ---- Q/K: LDS stage -> coalesced Out[z][lseq][d] (16B stores) ----
    ushort* Out = (zid == 0) ? Qo : Ko;
    const float sc = (zid == 0) ? 0.125f : 1.f;
#pragma unroll
    for (int nbp = 0; nbp < 2; ++nbp) {
#pragma unroll
      for (int hh = 0; hh < 2; ++hh) {
        __syncthreads();
        if (wc == hh) {
#pragma unroll
          for (int m = 0; m < 4; ++m)
#pragma unroll
            for (int n = 0; n < 4; ++n)
#pragma unroll
              for (int rr = 0; rr < 2; ++rr) {
                const int r = nbp + 2 * rr;
                st[(wr * 32 + m * 8 + 2 * lg + rr) * 72 + n * 16 + lr] =
                    f2bf((acc[m][n][r] + biasn[n]) * sc);
              }
        }
        __syncthreads();
        const int zz = nbp * HEADS + (nbase >> 6) + hh;
#pragma unroll
        for (int it = 0; it < 2; ++it) {
          const int c = it * 256 + tid;          // 0..511
          const int lr2 = c >> 3, cc8 = c & 7;
          const short8 v = *(const short8*)&st[lr2 * 72 + cc8 * 8];
          *(short8*)&Out[((size_t)zz * L_SEQ + (mbase >> 1) + lr2) * DH + cc8 * 8] = v;
        }
      }
    }
  }
}

// ---------------- block-sparse attention ----------------
// Middle WGs (bid < 32*62): one per (z, qb in [2,64)), 7 slots, write O.
// Head WGs (bid >= 32*62): split-K — one per (z, qb in {0,1}, split in [0,8)),
// 8 key blocks each; write unnormalized partial O + per-row m,l to ws.
__global__ __launch_bounds__(256)
void attn_sparse(const ushort* __restrict__ Q, const ushort* __restrict__ K,
                 const ushort* __restrict__ Vt, const int* __restrict__ rnd,
                 ushort* __restrict__ O,
                 float* __restrict__ Pp, float* __restrict__ Mp,
                 float* __restrict__ Lp) {
  const int bid = blockIdx.x;
  int z, qb, split = 0;
  bool head;
  if (bid < Z_DIM * 62) {
    z = bid / 62; qb = bid % 62 + 2; head = false;
  } else {
    const int t = bid - Z_DIM * 62;          // 0..511
    z = t >> 4; qb = (t >> 3) & 1; split = t & 7; head = true;
  }
  const int tid = threadIdx.x;
  const int w = tid >> 6, l = tid & 63;
  const int lr = l & 15, lg = l >> 4;

  __shared__ ushort Kl[64 * 64];
  __shared__ ushort Vl[64 * 64];
  __shared__ ushort Pl[4][16 * 64];

  const ushort* Qbase = Q + ((size_t)z * L_SEQ + qb * 64 + w * 16) * DH;
  const short8 aq0 = *(const short8*)(Qbase + lr * DH + lg * 8);
  const short8 aq1 = *(const short8*)(Qbase + lr * DH + 32 + lg * 8);

  float m[4], lsum[4];
  f32x4 accO[4];
#pragma unroll
  for (int r = 0; r < 4; ++r) { m[r] = -1e30f; lsum[r] = 0.f; }
#pragma unroll
  for (int t = 0; t < 4; ++t) accO[t] = (f32x4){0.f, 0.f, 0.f, 0.f};

  const int nslot = head ? 8 : 7;
  int sk[3] = {0, 0, 0}, sv[3] = {0, 0, 0}, rk0 = 0, rk1 = 0;
  if (!head) {
    const int i = qb - 2;
    rk0 = rnd[2 * i]; rk1 = rnd[2 * i + 1];
    if (qb < NBLK - 1) {
      sk[0] = qb - 1; sk[1] = qb; sk[2] = qb + 1;
      sv[0] = qb - 1; sv[1] = qb; sv[2] = qb + 1;
    } else {  // bottom row: K = {ZERO, 62, 63}, V = {62, 63, ZERO}
      sk[0] = -1; sk[1] = NBLK - 2; sk[2] = NBLK - 1;
      sv[0] = NBLK - 2; sv[1] = NBLK - 1; sv[2] = -1;
    }
  }

  for (int slot = 0; slot < nslot; ++slot) {
    int ki, vi;
    if (head) { ki = split * 8 + slot; vi = ki; }
    else if (slot < 2) { ki = slot; vi = slot; }
    else if (slot < 5) { ki = sk[slot - 2]; vi = sv[slot - 2]; }
    else { ki = (slot == 5) ? rk0 : rk1; vi = ki; }

    if (slot) __syncthreads();  // all waves done reading Kl/Vl
#pragma unroll
    for (int s = 0; s < 2; ++s) {
      const int chunk = s * 256 + tid;
      const int row = chunk >> 3, cc = chunk & 7;
      const int scc = cc ^ (row & 7);  // pre-swizzled global source
      if (ki >= 0)
        gload_lds16(K + ((size_t)z * L_SEQ + ki * 64 + row) * DH + scc * 8,
                    &Kl[(s * 256 + (tid & ~63)) * 8]);
      if (vi >= 0)
        gload_lds16(Vt + ((size_t)z * DH + row) * L_SEQ + vi * 64 + scc * 8,
                    &Vl[(s * 256 + (tid & ~63)) * 8]);
    }
    __syncthreads();

    // scores: S[q][key] for 16 q-rows x 64 keys
    f32x4 sc[4];
    if (ki >= 0) {
#pragma unroll
      for (int t = 0; t < 4; ++t) {
        const int r = t * 16 + lr;
        const short8 b0 = *(const short8*)&Kl[r * 64 + ((lg ^ (r & 7)) << 3)];
        const short8 b1 = *(const short8*)&Kl[r * 64 + (((4 + lg) ^ (r & 7)) << 3)];
        f32x4 zz = (f32x4){0.f, 0.f, 0.f, 0.f};
        sc[t] = __builtin_amdgcn_mfma_f32_16x16x32_bf16(aq0, b0, zz, 0, 0, 0);
        sc[t] = __builtin_amdgcn_mfma_f32_16x16x32_bf16(aq1, b1, sc[t], 0, 0, 0);
      }
    } else {
#pragma unroll
      for (int t = 0; t < 4; ++t) sc[t] = (f32x4){0.f, 0.f, 0.f, 0.f};
    }

    // online softmax (rows owned by 16-lane groups; reduce via shfl_xor)
#pragma unroll
    for (int r = 0; r < 4; ++r) {
      float sm = fmaxf(fmaxf(sc[0][r], sc[1][r]), fmaxf(sc[2][r], sc[3][r]));
      sm = fmaxf(sm, __shfl_xor(sm, 1));
      sm = fmaxf(sm, __shfl_xor(sm, 2));
      sm = fmaxf(sm, __shfl_xor(sm, 4));
      sm = fmaxf(sm, __shfl_xor(sm, 8));
      const float mn = fmaxf(m[r], sm);
      const float scale = __expf(m[r] - mn);
      m[r] = mn;
      lsum[r] *= scale;
#pragma unroll
      for (int t = 0; t < 4; ++t) accO[t][r] *= scale;
      float psum = 0.f;
#pragma unroll
      for (int t = 0; t < 4; ++t) {
        const float p = __expf(sc[t][r] - mn);
        sc[t][r] = p;
        psum += p;
      }
      lsum[r] += psum;
    }

    if (vi >= 0) {
      // P -> bf16 -> per-wave swizzled LDS, then read back as A-fragments
      ushort* P = &Pl[w][0];
#pragma unroll
      for (int t = 0; t < 4; ++t) {
#pragma unroll
        for (int r = 0; r < 4; ++r) {
          const int prow = 4 * lg + r, pcol = lr + 16 * t;
          P[prow * 64 + (((pcol >> 3) ^ (prow & 7)) << 3) + (pcol & 7)] = f2bf(sc[t][r]);
        }
      }
      const short8 ap0 = *(const short8*)&P[lr * 64 + ((lg ^ (lr & 7)) << 3)];
      const short8 ap1 = *(const short8*)&P[lr * 64 + (((4 + lg) ^ (lr & 7)) << 3)];
#pragma unroll
      for (int t = 0; t < 4; ++t) {
        const int r = t * 16 + lr;
        const short8 bv0 = *(const short8*)&Vl[r * 64 + ((lg ^ (r & 7)) << 3)];
        const short8 bv1 = *(const short8*)&Vl[r * 64 + (((4 + lg) ^ (r & 7)) << 3)];
        accO[t] = __builtin_amdgcn_mfma_f32_16x16x32_bf16(ap0, bv0, accO[t], 0, 0, 0);
        accO[t] = __builtin_amdgcn_mfma_f32_16x16x32_bf16(ap1, bv1, accO[t], 0, 0, 0);
      }
    }
  }

  // row sums across 16 lanes
#pragma unroll
  for (int r = 0; r < 4; ++r) {
    float s = lsum[r];
    s += __shfl_xor(s, 1);
    s += __shfl_xor(s, 2);
    s += __shfl_xor(s, 4);
    s += __shfl_xor(s, 8);
    lsum[r] = s;
  }

  if (!head) {
    const int nb = z >> 4, hd = z & 15;
#pragma unroll
    for (int t = 0; t < 4; ++t) {
#pragma unroll
      for (int r = 0; r < 4; ++r) {
        const int lseq = qb * 64 + w * 16 + 4 * lg + r;
        O[((size_t)lseq * NBATCH + nb) * HID + hd * 64 + lr + 16 * t] =
            f2bf(accO[t][r] / lsum[r]);
      }
    }
  } else {
    const int hbase = (qb * Z_DIM + z) * NSPLIT + split;
#pragma unroll
    for (int t = 0; t < 4; ++t) {
#pragma unroll
      for (int r = 0; r < 4; ++r) {
        const int row = w * 16 + 4 * lg + r;   // 0..63 within the q-block
        Pp[((size_t)hbase * 64 + row) * 64 + lr + 16 * t] = accO[t][r];
      }
    }
    if (lr == 0) {
#pragma unroll
      for (int r = 0; r < 4; ++r) {
        const int row = w * 16 + 4 * lg + r;
        Mp[hbase * 64 + row] = m[r];
        Lp[hbase * 64 + row] = lsum[r];
      }
    }
  }
}

// ---------------- combine head split-K partials ----------------
// grid: 64 WGs = (z, qb); thread owns (row, 16 cols).
__global__ __launch_bounds__(256)
void head_reduce(const float* __restrict__ Pp, const float* __restrict__ Mp,
                 const float* __restrict__ Lp, ushort* __restrict__ O) {
  const int z = blockIdx.x >> 1, qb = blockIdx.x & 1;
  const int tid = threadIdx.x;
  const int row = tid >> 2, cg = tid & 3;
  const int base = (qb * Z_DIM + z) * NSPLIT;

  float mm[NSPLIT], wgt[NSPLIT];
  float mx = -1e30f;
#pragma unroll
  for (int s = 0; s < NSPLIT; ++s) {
    mm[s] = Mp[(base + s) * 64 + row];
    mx = fmaxf(mx, mm[s]);
  }
  float denom = 0.f;
#pragma unroll
  for (int s = 0; s < NSPLIT; ++s) {
    wgt[s] = __expf(mm[s] - mx);
    denom += Lp[(base + s) * 64 + row] * wgt[s];
  }
  const float inv = 1.f / denom;

  const int nb = z >> 4, hd = z & 15;
  const int lseq = qb * 64 + row;
#pragma unroll
  for (int c = 0; c < 16; ++c) {
    const int col = cg * 16 + c;
    float acc = 0.f;
#pragma unroll
    for (int s = 0; s < NSPLIT; ++s)
      acc += Pp[((size_t)(base + s) * 64 + row) * 64 + col] * wgt[s];
    O[((size_t)lseq * NBATCH + nb) * HID + hd * 64 + col] = f2bf(acc * inv);
  }
}

extern "C" void kernel_launch(void* const* d_in, const int* in_sizes, int n_in,
                              void* d_out, int out_size, void* d_ws, size_t ws_size,
                              hipStream_t stream) {
  (void)in_sizes; (void)n_in; (void)out_size; (void)ws_size;
  const float* query    = (const float*)d_in[0];
  const float* q_proj   = (const float*)d_in[1];
  const float* q_bias   = (const float*)d_in[2];
  const float* k_proj   = (const float*)d_in[3];
  const float* k_bias   = (const float*)d_in[4];
  const float* v_proj   = (const float*)d_in[5];
  const float* v_bias   = (const float*)d_in[6];
  const float* out_proj = (const float*)d_in[7];
  const float* out_bias = (const float*)d_in[8];
  const int*   rnd      = (const int*)d_in[9];

  ushort* Xb  = (ushort*)d_ws;                         // [8192][1024] bf16
  ushort* Wq  = Xb + (size_t)NROWS * HID;
  ushort* Wk  = Wq + (size_t)HID * HID;
  ushort* Wv  = Wk + (size_t)HID * HID;
  ushort* Wo  = Wv + (size_t)HID * HID;
  ushort* Qb  = Wo + (size_t)HID * HID;                // [Z][L][64]
  ushort* Kb  = Qb + (size_t)Z_DIM * L_SEQ * DH;       // [Z][L][64]
  ushort* Vtb = Kb + (size_t)Z_DIM * L_SEQ * DH;       // [Z][64][L]
  float*  Pp  = (float*)(Vtb + (size_t)Z_DIM * DH * L_SEQ);  // head partials
  float*  Mp  = Pp + (size_t)2 * Z_DIM * NSPLIT * 64 * 64;
  float*  Lp  = Mp + (size_t)2 * Z_DIM * NSPLIT * 64;
  ushort* Ob  = Xb;  // alias: X dead after QKV GEMM, O written by attn
  float*  Fo  = (float*)d_out;

  cvt_multi<<<(NROWS * HID / 4 + 4 * HID * HID / 4) / 256, 256, 0, stream>>>(
      query, Xb, q_proj, Wq, k_proj, Wk, v_proj, Wv, out_proj, Wo);

  gemm_bt<0><<<1536, 256, 0, stream>>>(
      Xb, Wq, Wk, Wv, q_bias, k_bias, v_bias, Qb, Kb, Vtb, nullptr);

  attn_sparse<<<Z_DIM * 62 + 2 * Z_DIM * NSPLIT, 256, 0, stream>>>(
      Qb, Kb, Vtb, rnd, Ob, Pp, Mp, Lp);

  head_reduce<<<2 * Z_DIM, 256, 0, stream>>>(Pp, Mp, Lp, Ob);

  gemm_bt<1><<<512, 256, 0, stream>>>(
      Ob, Wo, nullptr, nullptr, out_bias, nullptr, nullptr,
      nullptr, nullptr, nullptr, Fo);
}